// Round 9
// baseline (159.013 us; speedup 1.0000x reference)
//
#include <hip/hip_runtime.h>
#include <math.h>

#define NU 20000
#define NI 20000
#define NT 5000
#define NN 45000
#define D  64
#define CAP 64
#define MBLK 704      // ceil(NN/64) mlp blocks
#define EPB 1024      // edges per scatter block (4 per thread)

typedef unsigned short u16;
typedef unsigned int u32;

typedef __attribute__((ext_vector_type(8))) short bf16x8;
typedef __attribute__((ext_vector_type(4))) float f32x4;

__device__ __forceinline__ float b2f(u16 u) {
  return __uint_as_float(((u32)u) << 16);
}
__device__ __forceinline__ u16 f2b(float f) {
  u32 x = __float_as_uint(f);
  u32 r = (x + 0x7fffu + ((x >> 16) & 1u)) >> 16;
  return (u16)r;
}
__device__ __forceinline__ const float* row3(int n, const float* a, const float* b, const float* c) {
  if (n < NU) return a + (size_t)n * D;
  if (n < NU + NI) return b + (size_t)(n - NU) * D;
  return c + (size_t)(n - NU - NI) * D;
}
__device__ __forceinline__ bf16x8 cvtf8(const float* p) {
  bf16x8 r;
#pragma unroll
  for (int j = 0; j < 8; ++j) r[j] = (short)f2b(p[j]);
  return r;
}

// ---------------- MLP body: PEO[node*64+f] = {p = exp(clamp(mlp(x))), e|o<<16} ----------------
template <int FIRST>
__device__ __forceinline__ void mlp_body(
    int bid,
    const float* __restrict__ ue, const float* __restrict__ ie, const float* __restrict__ te,
    const float* __restrict__ uo, const float* __restrict__ io, const float* __restrict__ to,
    const u16* __restrict__ Xc, const u16* __restrict__ O2,
    const float* __restrict__ W1, const float* __restrict__ b1,
    const float* __restrict__ W2, const float* __restrict__ b2,
    uint2* __restrict__ PEO) {
  __shared__ u16 W1L[64][72];
  __shared__ u16 W2L[64][72];
  __shared__ u16 Hs[64][72];
  int tid = threadIdx.x;
  for (int i = tid; i < 4096; i += 256) {
    W1L[i >> 6][i & 63] = f2b(W1[i]);
    W2L[i >> 6][i & 63] = f2b(W2[i]);
  }
  __syncthreads();
  int w = tid >> 6, l = tid & 63;
  int lr = l & 15, kh = l >> 4;
  int nbase = bid * 64 + w * 16;
  int na = nbase + lr; if (na > NN - 1) na = NN - 1;
  bf16x8 A0, A1;
  if (FIRST) {
    const float* xr = row3(na, ue, ie, te);
    A0 = cvtf8(xr + kh * 8);
    A1 = cvtf8(xr + 32 + kh * 8);
  } else {
    A0 = *(const bf16x8*)(Xc + (size_t)na * 64 + kh * 8);
    A1 = *(const bf16x8*)(Xc + (size_t)na * 64 + 32 + kh * 8);
  }
#pragma unroll
  for (int ft = 0; ft < 4; ++ft) {
    int f = ft * 16 + lr;
    bf16x8 Bl = *(const bf16x8*)&W1L[f][kh * 8];
    bf16x8 Bh = *(const bf16x8*)&W1L[f][32 + kh * 8];
    f32x4 z = {0.f, 0.f, 0.f, 0.f};
    z = __builtin_amdgcn_mfma_f32_16x16x32_bf16(A0, Bl, z, 0, 0, 0);
    z = __builtin_amdgcn_mfma_f32_16x16x32_bf16(A1, Bh, z, 0, 0, 0);
    float bb = b1[f];
#pragma unroll
    for (int r = 0; r < 4; ++r)
      Hs[w * 16 + kh * 4 + r][f] = f2b(fmaxf(z[r] + bb, 0.f));
  }
  __syncthreads();
  bf16x8 A20 = *(const bf16x8*)&Hs[w * 16 + lr][kh * 8];
  bf16x8 A21 = *(const bf16x8*)&Hs[w * 16 + lr][32 + kh * 8];
#pragma unroll
  for (int ft = 0; ft < 4; ++ft) {
    int f = ft * 16 + lr;
    bf16x8 Bl = *(const bf16x8*)&W2L[f][kh * 8];
    bf16x8 Bh = *(const bf16x8*)&W2L[f][32 + kh * 8];
    f32x4 z = {0.f, 0.f, 0.f, 0.f};
    z = __builtin_amdgcn_mfma_f32_16x16x32_bf16(A20, Bl, z, 0, 0, 0);
    z = __builtin_amdgcn_mfma_f32_16x16x32_bf16(A21, Bh, z, 0, 0, 0);
    float bb = b2[f];
#pragma unroll
    for (int r = 0; r < 4; ++r) {
      int node = nbase + kh * 4 + r;
      if (node < NN) {
        float a = z[r] + bb;
        float p = __expf(fminf(fmaxf(a, -60.f), 60.f));
        u32 eo;
        if (FIRST) {
          float ev = row3(node, ue, ie, te)[f];
          float ov = fmaxf(row3(node, uo, io, to)[f], 0.f);
          eo = (u32)f2b(ev) | ((u32)f2b(ov) << 16);
        } else {
          u32 idx = ((u32)node << 6) + f;
          eo = (u32)Xc[idx] | ((u32)O2[idx] << 16);
        }
        uint2 v; v.x = __float_as_uint(p); v.y = eo;
        PEO[((size_t)node << 6) + f] = v;
      }
    }
  }
}

// ---------------- fused1: mlp hop-1 + ILP-batched CSR scatter ----------------
__global__ __launch_bounds__(256) void fused1_kernel(
    const float* __restrict__ ue, const float* __restrict__ ie, const float* __restrict__ te,
    const float* __restrict__ uo, const float* __restrict__ io, const float* __restrict__ to,
    const float* __restrict__ W1, const float* __restrict__ b1,
    const float* __restrict__ W2, const float* __restrict__ b2,
    const int* __restrict__ head, const int* __restrict__ tail, int E,
    uint2* __restrict__ PEO, int* __restrict__ cnt, u16* __restrict__ csr) {
  int bid = blockIdx.x;
  if (bid >= MBLK) {
    // 4 edges/thread: batch loads, then 4 independent atomics in flight, then stores.
    int base = (bid - MBLK) * EPB + threadIdx.x;
    int h0 = -1, h1 = -1, h2 = -1, h3 = -1;
    int t0 = 0, t1 = 0, t2 = 0, t3 = 0;
    if (base < E)       { h0 = head[base];       t0 = tail[base]; }
    if (base + 256 < E) { h1 = head[base + 256]; t1 = tail[base + 256]; }
    if (base + 512 < E) { h2 = head[base + 512]; t2 = tail[base + 512]; }
    if (base + 768 < E) { h3 = head[base + 768]; t3 = tail[base + 768]; }
    int s0 = CAP, s1 = CAP, s2 = CAP, s3 = CAP;
    if (h0 >= 0) s0 = atomicAdd(&cnt[h0], 1);
    if (h1 >= 0) s1 = atomicAdd(&cnt[h1], 1);
    if (h2 >= 0) s2 = atomicAdd(&cnt[h2], 1);
    if (h3 >= 0) s3 = atomicAdd(&cnt[h3], 1);
    if (s0 < CAP) csr[h0 * CAP + s0] = (u16)t0;
    if (s1 < CAP) csr[h1 * CAP + s1] = (u16)t1;
    if (s2 < CAP) csr[h2 * CAP + s2] = (u16)t2;
    if (s3 < CAP) csr[h3 * CAP + s3] = (u16)t3;
    return;
  }
  mlp_body<1>(bid, ue, ie, te, uo, io, to, nullptr, nullptr, W1, b1, W2, b2, PEO);
}

__global__ __launch_bounds__(256) void mlp2_kernel(
    const u16* __restrict__ Xc, const u16* __restrict__ O2,
    const float* __restrict__ W1, const float* __restrict__ b1,
    const float* __restrict__ W2, const float* __restrict__ b2,
    uint2* __restrict__ PEO) {
  mlp_body<0>(blockIdx.x, nullptr, nullptr, nullptr, nullptr, nullptr, nullptr,
              Xc, O2, W1, b1, W2, b2, PEO);
}

// ---------------- aggregation: one wave per node, merged roles, 8-deep ILP ----------------
template <int FINAL>
__global__ __launch_bounds__(256) void agg_kernel(
    const int* __restrict__ cnt, const u16* __restrict__ csr,
    const uint2* __restrict__ PEO,
    u16* __restrict__ Xco, u16* __restrict__ Oo, float* __restrict__ out) {
  int n = (blockIdx.x * blockDim.x + threadIdx.x) >> 6;
  int lane = threadIdx.x & 63;
  if (n >= NN) return;
  int cn = min(cnt[n], CAP);
  int tl = (lane < cn) ? (int)csr[n * CAP + lane] : 0;
  const char* Pb = (const char*)PEO;
  size_t lo = (size_t)(lane << 3);
  float ss0 = 0.f, ss1 = 0.f, ss2 = 0.f, ss3 = 0.f;
  float ts0 = 0.f, ts1 = 0.f, ts2 = 0.f, ts3 = 0.f;
  float mn0 = 3.4e38f, mn1 = 3.4e38f;
  float mx0 = -3.4e38f, mx1 = -3.4e38f;

#define LD(T) (*(const uint2*)(Pb + ((size_t)(u32)(T) << 9) + lo))
#define ACC(V, SS, TS)                                  \
  { float p_ = __uint_as_float((V).x);                  \
    float e_ = b2f((u16)((V).y & 0xffffu));             \
    SS += p_; TS = fmaf(p_, e_, TS); }
#define OV(V) b2f((u16)((V).y >> 16))

  if (n < NU) {
    int j = 0;
    for (; j + 7 < cn; j += 8) {
      int t0 = __shfl(tl, j),     t1 = __shfl(tl, j + 1);
      int t2 = __shfl(tl, j + 2), t3 = __shfl(tl, j + 3);
      int t4 = __shfl(tl, j + 4), t5 = __shfl(tl, j + 5);
      int t6 = __shfl(tl, j + 6), t7 = __shfl(tl, j + 7);
      uint2 v0 = LD(t0), v1 = LD(t1), v2 = LD(t2), v3 = LD(t3);
      uint2 v4 = LD(t4), v5 = LD(t5), v6 = LD(t6), v7 = LD(t7);
      ACC(v0, ss0, ts0) ACC(v1, ss1, ts1) ACC(v2, ss2, ts2) ACC(v3, ss3, ts3)
      ACC(v4, ss0, ts0) ACC(v5, ss1, ts1) ACC(v6, ss2, ts2) ACC(v7, ss3, ts3)
      if (t0 >= NU + NI) mx0 = fmaxf(mx0, OV(v0)); else if (t0 >= NU) mn0 = fminf(mn0, OV(v0));
      if (t1 >= NU + NI) mx1 = fmaxf(mx1, OV(v1)); else if (t1 >= NU) mn1 = fminf(mn1, OV(v1));
      if (t2 >= NU + NI) mx0 = fmaxf(mx0, OV(v2)); else if (t2 >= NU) mn0 = fminf(mn0, OV(v2));
      if (t3 >= NU + NI) mx1 = fmaxf(mx1, OV(v3)); else if (t3 >= NU) mn1 = fminf(mn1, OV(v3));
      if (t4 >= NU + NI) mx0 = fmaxf(mx0, OV(v4)); else if (t4 >= NU) mn0 = fminf(mn0, OV(v4));
      if (t5 >= NU + NI) mx1 = fmaxf(mx1, OV(v5)); else if (t5 >= NU) mn1 = fminf(mn1, OV(v5));
      if (t6 >= NU + NI) mx0 = fmaxf(mx0, OV(v6)); else if (t6 >= NU) mn0 = fminf(mn0, OV(v6));
      if (t7 >= NU + NI) mx1 = fmaxf(mx1, OV(v7)); else if (t7 >= NU) mn1 = fminf(mn1, OV(v7));
    }
    for (; j < cn; ++j) {
      int t = __shfl(tl, j);
      uint2 v = LD(t);
      ACC(v, ss0, ts0)
      if (t >= NU + NI) mx0 = fmaxf(mx0, OV(v)); else if (t >= NU) mn0 = fminf(mn0, OV(v));
    }
  } else if (n < NU + NI) {
    int j = 0;
    for (; j + 7 < cn; j += 8) {
      int t0 = __shfl(tl, j),     t1 = __shfl(tl, j + 1);
      int t2 = __shfl(tl, j + 2), t3 = __shfl(tl, j + 3);
      int t4 = __shfl(tl, j + 4), t5 = __shfl(tl, j + 5);
      int t6 = __shfl(tl, j + 6), t7 = __shfl(tl, j + 7);
      uint2 v0 = LD(t0), v1 = LD(t1), v2 = LD(t2), v3 = LD(t3);
      uint2 v4 = LD(t4), v5 = LD(t5), v6 = LD(t6), v7 = LD(t7);
      ACC(v0, ss0, ts0) ACC(v1, ss1, ts1) ACC(v2, ss2, ts2) ACC(v3, ss3, ts3)
      ACC(v4, ss0, ts0) ACC(v5, ss1, ts1) ACC(v6, ss2, ts2) ACC(v7, ss3, ts3)
      mx0 = fmaxf(mx0, OV(v0)); mx1 = fmaxf(mx1, OV(v1));
      mx0 = fmaxf(mx0, OV(v2)); mx1 = fmaxf(mx1, OV(v3));
      mx0 = fmaxf(mx0, OV(v4)); mx1 = fmaxf(mx1, OV(v5));
      mx0 = fmaxf(mx0, OV(v6)); mx1 = fmaxf(mx1, OV(v7));
    }
    for (; j < cn; ++j) {
      int t = __shfl(tl, j);
      uint2 v = LD(t);
      ACC(v, ss0, ts0)
      mx0 = fmaxf(mx0, OV(v));
    }
  } else {
    int j = 0;
    for (; j + 7 < cn; j += 8) {
      int t0 = __shfl(tl, j),     t1 = __shfl(tl, j + 1);
      int t2 = __shfl(tl, j + 2), t3 = __shfl(tl, j + 3);
      int t4 = __shfl(tl, j + 4), t5 = __shfl(tl, j + 5);
      int t6 = __shfl(tl, j + 6), t7 = __shfl(tl, j + 7);
      uint2 v0 = LD(t0), v1 = LD(t1), v2 = LD(t2), v3 = LD(t3);
      uint2 v4 = LD(t4), v5 = LD(t5), v6 = LD(t6), v7 = LD(t7);
      ACC(v0, ss0, ts0) ACC(v1, ss1, ts1) ACC(v2, ss2, ts2) ACC(v3, ss3, ts3)
      ACC(v4, ss0, ts0) ACC(v5, ss1, ts1) ACC(v6, ss2, ts2) ACC(v7, ss3, ts3)
      mn0 = fminf(mn0, OV(v0)); mn1 = fminf(mn1, OV(v1));
      mn0 = fminf(mn0, OV(v2)); mn1 = fminf(mn1, OV(v3));
      mn0 = fminf(mn0, OV(v4)); mn1 = fminf(mn1, OV(v5));
      mn0 = fminf(mn0, OV(v6)); mn1 = fminf(mn1, OV(v7));
    }
    for (; j < cn; ++j) {
      int t = __shfl(tl, j);
      uint2 v = LD(t);
      ACC(v, ss0, ts0)
      mn0 = fminf(mn0, OV(v));
    }
  }
#undef LD
#undef ACC
#undef OV

  float ssum = (ss0 + ss1) + (ss2 + ss3);
  float tsum = (ts0 + ts1) + (ts2 + ts3);
  float omin = fminf(mn0, mn1), omax = fmaxf(mx0, mx1);
  float agg = tsum / ssum;
  float sq = agg * agg;
#pragma unroll
  for (int msk = 1; msk < 64; msk <<= 1) sq += __shfl_xor(sq, msk);
  float outv = agg / fmaxf(sqrtf(sq), 1e-12f);
  float offv;
  if (n < NU) {
    float iu = (omin > 1e37f) ? 0.f : omin;
    float ut = (omax < -1e37f) ? 0.f : omax;
    offv = fmaxf(fminf(iu, ut), 0.f);
  } else if (n < NU + NI) {
    offv = fmaxf((omax < -1e37f) ? 0.f : omax, 0.f);
  } else {
    offv = fmaxf((omin > 1e37f) ? 0.f : omin, 0.f);
  }
  if (FINAL) {
    float* oe; float* oo;
    if (n < NU)           { oe = out + (size_t)n * D;
                            oo = out + (size_t)NU * D + (size_t)n * D; }
    else if (n < NU + NI) { int q = n - NU;
                            oe = out + (size_t)2 * NU * D + (size_t)q * D;
                            oo = oe + (size_t)NI * D; }
    else                  { int q = n - NU - NI;
                            oe = out + (size_t)(2 * NU + 2 * NI) * D + (size_t)q * D;
                            oo = oe + (size_t)NT * D; }
    __builtin_nontemporal_store(outv, &oe[lane]);
    __builtin_nontemporal_store(offv, &oo[lane]);
  } else {
    u32 idx = ((u32)n << 6) + lane;
    Xco[idx] = f2b(outv);
    Oo[idx] = f2b(offv);
  }
}

extern "C" void kernel_launch(void* const* d_in, const int* in_sizes, int n_in,
                              void* d_out, int out_size, void* d_ws, size_t ws_size,
                              hipStream_t stream) {
  const float* ue = (const float*)d_in[0];
  const float* uo = (const float*)d_in[1];
  const float* ie = (const float*)d_in[2];
  const float* io = (const float*)d_in[3];
  const float* te = (const float*)d_in[4];
  const float* to = (const float*)d_in[5];
  const float* W1 = (const float*)d_in[6];
  const float* b1 = (const float*)d_in[7];
  const float* W2 = (const float*)d_in[8];
  const float* b2 = (const float*)d_in[9];
  const int* head = (const int*)d_in[10];
  const int* tail = (const int*)d_in[11];
  int E = in_sizes[10];

  const size_t NE = (size_t)NN * 64;
  uint2* PEO = (uint2*)d_ws;            // NE uint2 (23 MB, reused across hops)
  u16* Xc  = (u16*)(PEO + NE);          // NE u16
  u16* O2  = Xc + NE;                   // NE u16
  int* cnt = (int*)(O2 + NE);           // NN
  u16* csr = (u16*)(cnt + NN);          // NN*CAP u16

  hipMemsetAsync(cnt, 0, NN * sizeof(int), stream);
  int nsb = (E + EPB - 1) / EPB;        // 630 scatter blocks

  // hop 1: fused {W-convert + MLP + PEO pack} || ILP-batched CSR scatter
  fused1_kernel<<<MBLK + nsb, 256, 0, stream>>>(
      ue, ie, te, uo, io, to, W1, b1, W2, b2, head, tail, E, PEO, cnt, csr);
  int ab = (NN + 3) / 4;
  agg_kernel<0><<<ab, 256, 0, stream>>>(cnt, csr, PEO, Xc, O2, nullptr);

  // hop 2
  mlp2_kernel<<<MBLK, 256, 0, stream>>>(Xc, O2, W1, b1, W2, b2, PEO);
  agg_kernel<1><<<ab, 256, 0, stream>>>(cnt, csr, PEO, nullptr, nullptr, (float*)d_out);
}